// Round 12
// baseline (164.562 us; speedup 1.0000x reference)
//
#include <hip/hip_runtime.h>
#include <hip/hip_fp16.h>

// GCN 2-layer forward. N=100000 nodes, E=1600000 directed edges.
// out[c] = relu( dinv[c] * ( sum_{r->c} g[r] + g[c] ) + b ),  g = (x@W)*dinv
// dinv = rsqrt(indeg+1) (self-loops folded in analytically).
// Round 12: revert R11's build regressions (CHUNK back to 8192 — 4096 broke
// the >=16-entries-per-line run invariant and doubled reservation atomics;
// ebuf LDS staging restored). NEW: per-bucket degree-ordered node scheduling.
// bucket_sort counting-sorts its 256 nodes by degree (64 bins) into
// perm[bucket*256+rank]; the gathers process perm order, so each wave's 16
// nodes have near-equal degree -> gather-loop divergence ~eliminated.

constexpr int NN  = 100000;
constexpr int FIN = 16;
constexpr int FH  = 32;   // hidden
constexpr int FO  = 16;   // layer-2 out

constexpr int BK      = 256;                     // nodes per bucket (col>>8)
constexpr int NBUCKET = (NN + BK - 1) / BK;      // 391
constexpr int NSLOT   = NBUCKET * BK;            // 100096 perm slots
constexpr int CHUNK   = 8192;                    // edges per fill block (196 blocks)
constexpr int CAP     = 5376;                    // bucket segment capacity (mean 4092, +20 sigma)

static __device__ __forceinline__ int pack2(float a, float b) {
    __half2 t = __float22half2_rn(make_float2(a, b));
    return *reinterpret_cast<int*>(&t);
}
static __device__ __forceinline__ float2 unpack2(int v) {
    __half2 t = *reinterpret_cast<__half2*>(&v);
    return __half22float2(t);
}

// ---- init: bcursor[b] = b*CAP ----
__global__ void init_kernel(int* __restrict__ bcursor) {
    int b = blockIdx.x * blockDim.x + threadIdx.x;
    if (b < NBUCKET) bcursor[b] = b * CAP;
}

// ---- phase A: bucket fill into fixed segments. Per-block run reservation. ----
__global__ __launch_bounds__(256) void bucket_fill_kernel(
        const int* __restrict__ row, const int* __restrict__ col,
        int* __restrict__ bcursor, int* __restrict__ srow, int E) {
    __shared__ int bcnt[NBUCKET];
    __shared__ int bcur[NBUCKET];
    int t = threadIdx.x;
    int e0 = blockIdx.x * CHUNK;
    int m = E - e0; if (m > CHUNK) m = CHUNK;
    for (int b = t; b < NBUCKET; b += 256) bcnt[b] = 0;
    __syncthreads();
    for (int i = t; i < m; i += 256)
        atomicAdd(&bcnt[col[e0 + i] >> 8], 1);
    __syncthreads();
    for (int b = t; b < NBUCKET; b += 256) {
        int v = bcnt[b];
        bcur[b] = v ? atomicAdd(&bcursor[b], v) : 0;   // contiguous run for this block
    }
    __syncthreads();
    for (int i = t; i < m; i += 256) {
        int c = col[e0 + i];
        int r = row[e0 + i];
        int p = atomicAdd(&bcur[c >> 8], 1);
        srow[p] = ((c & (BK - 1)) << 17) | r;          // pack (c_local, r); r < 2^17
    }
}

// ---- phase B: per-bucket LDS counting sort; emits offcnt/dinv/g1 AND the
// degree-ordered perm (64-bin counting sort of the bucket's 256 nodes).
__global__ __launch_bounds__(256) void bucket_sort_mm1_kernel(
        const int* __restrict__ bcursor, int* __restrict__ srow,
        int2* __restrict__ offcnt, float* __restrict__ dinv,
        int* __restrict__ perm,
        const float* __restrict__ x, const float* __restrict__ W1,
        __half* __restrict__ g1, int n) {
    __shared__ int ebuf[CAP];
    __shared__ int sorted[CAP];
    __shared__ int cnt2[BK];
    __shared__ int aux[BK];
    __shared__ int dh[64];
    __shared__ int dbase[64];
    __shared__ float w1[FIN * FH];
    int t = threadIdx.x;
    for (int i = t; i < FIN * FH; i += 256) w1[i] = W1[i];
    if (t < 64) dh[t] = 0;
    int lo = blockIdx.x << 8;
    int nodes = n - lo; if (nodes > BK) nodes = BK;
    int s0 = blockIdx.x * CAP;
    int m = bcursor[blockIdx.x] - s0;                  // total edges in this bucket
    if (m > CAP) m = CAP;                              // paranoia guard (never hit)
    for (int i = t; i < m; i += 256) ebuf[i] = srow[s0 + i];
    cnt2[t] = 0;
    __syncthreads();
    for (int i = t; i < m; i += 256) atomicAdd(&cnt2[ebuf[i] >> 17], 1);
    __syncthreads();
    int v = cnt2[t];
    aux[t] = v;
    __syncthreads();
    for (int d = 1; d < BK; d <<= 1) {
        int a = (t >= d) ? aux[t - d] : 0;
        __syncthreads();
        aux[t] += a;
        __syncthreads();
    }
    int excl = aux[t] - v;
    cnt2[t] = excl;                                    // cursor for scatter
    float di = rsqrtf((float)v + 1.0f);
    if (t < nodes) {                                   // per-node CSR metadata, free
        offcnt[lo + t] = make_int2(s0 + excl, v);
        dinv[lo + t]   = di;
    }
    // ---- degree-ordered perm: counting sort 256 nodes by degree (64 bins) ----
    int dv = (t < nodes) ? (v > 63 ? 63 : v) : 0;      // dead slots bin 0
    atomicAdd(&dh[dv], 1);
    __syncthreads();
    if (t < 64) aux[t] = dh[t];                        // aux reuse (node-scan done)
    __syncthreads();
    for (int d = 1; d < 64; d <<= 1) {
        int a = (t >= d && t < 64) ? aux[t - d] : 0;
        __syncthreads();
        if (t < 64) aux[t] += a;
        __syncthreads();
    }
    if (t < 64) { dbase[t] = aux[t] - dh[t]; dh[t] = 0; }   // exclusive base; reset cursor
    __syncthreads();
    int rank = dbase[dv] + atomicAdd(&dh[dv], 1);
    perm[lo + rank] = (t < nodes) ? (lo + t) : -1;
    __syncthreads();
    // ---- permute edges node-ordered, write back ----
    for (int i = t; i < m; i += 256) {
        int pv = ebuf[i];
        int p = atomicAdd(&cnt2[pv >> 17], 1);
        sorted[p] = pv & 0x1FFFF;
    }
    __syncthreads();
    for (int i = t; i < m; i += 256) srow[s0 + i] = sorted[i];
    // ---- fused mm1: g1[lo+t] = fp16( (x[lo+t] @ W1) * di ) ----
    if (t < nodes) {
        int nd = lo + t;
        float xi[FIN];
        const float4* xv = (const float4*)(x + (long long)nd * FIN);
        #pragma unroll
        for (int i = 0; i < FIN / 4; i++) {
            float4 vv = xv[i];
            xi[4*i] = vv.x; xi[4*i+1] = vv.y; xi[4*i+2] = vv.z; xi[4*i+3] = vv.w;
        }
        float h[FH];
        #pragma unroll
        for (int j = 0; j < FH; j++) h[j] = 0.f;
        #pragma unroll
        for (int i = 0; i < FIN; i++) {
            float xs = xi[i];
            #pragma unroll
            for (int j = 0; j < FH; j++) h[j] += xs * w1[i * FH + j];
        }
        int4* gv = (int4*)(g1 + (long long)nd * FH);   // 64 B row
        #pragma unroll
        for (int k = 0; k < 4; k++) {
            gv[k] = make_int4(pack2(h[8*k]*di,   h[8*k+1]*di),
                              pack2(h[8*k+2]*di, h[8*k+3]*di),
                              pack2(h[8*k+4]*di, h[8*k+5]*di),
                              pack2(h[8*k+6]*di, h[8*k+7]*di));
        }
    }
}

// ---- fused gather layer1 (fp16 rows) + relu/bias + mm2 + scale -> g2 (fp16) ----
// block = 256 threads = 64 perm-slots x 4 lanes (lane = 8 feats = int4 = 16 B)
constexpr int XS = 36;   // LDS stride: 16B-aligned writes, 2-way (free) reads
__global__ __launch_bounds__(256) void gather_mm2_kernel(
        const int2* __restrict__ offcnt, const int* __restrict__ perm,
        const int* __restrict__ srow, const __half* __restrict__ g1,
        const float* __restrict__ dinv, const float* __restrict__ b1,
        const float* __restrict__ W2, __half* __restrict__ g2) {
    __shared__ float xs[64 * XS];          // 64 nodes x 32 feats (stride 36)
    __shared__ float w[FH * FO];           // 32x16
    __shared__ float bb[FH];
    int t = threadIdx.x;
    for (int i = t; i < FH * FO; i += 256) w[i] = W2[i];
    if (t < FH) bb[t] = b1[t];
    int nl = t >> 2;                       // slot-local 0..63
    int q = t & 3;                         // 8-feat group
    int node = perm[blockIdx.x * 64 + nl]; // degree-ordered schedule
    bool live = node >= 0;
    float acc[8] = {0.f,0.f,0.f,0.f,0.f,0.f,0.f,0.f};
    float di = 0.f;
    if (live) {
        di = dinv[node];
        {   // self-loop seed
            int4 raw = ((const int4*)(g1 + (long long)node * FH))[q];
            float2 f0 = unpack2(raw.x), f1 = unpack2(raw.y);
            float2 f2 = unpack2(raw.z), f3 = unpack2(raw.w);
            acc[0] = f0.x; acc[1] = f0.y; acc[2] = f1.x; acc[3] = f1.y;
            acc[4] = f2.x; acc[5] = f2.y; acc[6] = f3.x; acc[7] = f3.y;
        }
        int2 oc = offcnt[node];
        int s = oc.x, m = oc.y;
        int i = 0;
        for (; i + 3 < m; i += 4) {        // 4 indices then 4 16B rows in flight
            int r0 = srow[s + i];
            int r1 = srow[s + i + 1];
            int r2 = srow[s + i + 2];
            int r3 = srow[s + i + 3];
            int4 ra = ((const int4*)(g1 + (long long)r0 * FH))[q];
            int4 rb = ((const int4*)(g1 + (long long)r1 * FH))[q];
            int4 rc = ((const int4*)(g1 + (long long)r2 * FH))[q];
            int4 rd = ((const int4*)(g1 + (long long)r3 * FH))[q];
            float2 u;
            u = unpack2(ra.x); acc[0] += u.x; acc[1] += u.y;
            u = unpack2(ra.y); acc[2] += u.x; acc[3] += u.y;
            u = unpack2(ra.z); acc[4] += u.x; acc[5] += u.y;
            u = unpack2(ra.w); acc[6] += u.x; acc[7] += u.y;
            u = unpack2(rb.x); acc[0] += u.x; acc[1] += u.y;
            u = unpack2(rb.y); acc[2] += u.x; acc[3] += u.y;
            u = unpack2(rb.z); acc[4] += u.x; acc[5] += u.y;
            u = unpack2(rb.w); acc[6] += u.x; acc[7] += u.y;
            u = unpack2(rc.x); acc[0] += u.x; acc[1] += u.y;
            u = unpack2(rc.y); acc[2] += u.x; acc[3] += u.y;
            u = unpack2(rc.z); acc[4] += u.x; acc[5] += u.y;
            u = unpack2(rc.w); acc[6] += u.x; acc[7] += u.y;
            u = unpack2(rd.x); acc[0] += u.x; acc[1] += u.y;
            u = unpack2(rd.y); acc[2] += u.x; acc[3] += u.y;
            u = unpack2(rd.z); acc[4] += u.x; acc[5] += u.y;
            u = unpack2(rd.w); acc[6] += u.x; acc[7] += u.y;
        }
        for (; i < m; i++) {
            int r0 = srow[s + i];
            int4 ra = ((const int4*)(g1 + (long long)r0 * FH))[q];
            float2 u;
            u = unpack2(ra.x); acc[0] += u.x; acc[1] += u.y;
            u = unpack2(ra.y); acc[2] += u.x; acc[3] += u.y;
            u = unpack2(ra.z); acc[4] += u.x; acc[5] += u.y;
            u = unpack2(ra.w); acc[6] += u.x; acc[7] += u.y;
        }
    }
    __syncthreads();                       // w/bb loaded; also before xs write
    if (live) {
        // x1[8q..8q+7] = relu(acc*di + b1)
        float* xr = xs + nl * XS + 8 * q;
        #pragma unroll
        for (int j = 0; j < 8; j++) {
            float a = acc[j] * di + bb[8*q + j];
            xr[j] = a > 0.f ? a : 0.f;
        }
    }
    __syncthreads();
    if (live) {
        // lane q computes outputs k = 4q..4q+3 of x1 @ W2 (FO=16)
        const float* xr = xs + nl * XS;
        int k0 = 4 * q;
        float o0 = 0.f, o1 = 0.f, o2 = 0.f, o3 = 0.f;
        #pragma unroll
        for (int j = 0; j < FH; j++) {
            float xj = xr[j];
            const float* wr = w + j * FO + k0;
            o0 += xj * wr[0];
            o1 += xj * wr[1];
            o2 += xj * wr[2];
            o3 += xj * wr[3];
        }
        ((int2*)(g2 + (long long)node * FO))[q] =
            make_int2(pack2(o0 * di, o1 * di), pack2(o2 * di, o3 * di));
    }
}

// ---- fused gather layer2 (fp16 rows) + relu/bias + fc -> out ----
// block = 256 threads = 128 perm-slots x 2 lanes (lane = 8 feats = int4 = 16 B)
__global__ __launch_bounds__(256) void gather_fc_kernel(
        const int2* __restrict__ offcnt, const int* __restrict__ perm,
        const int* __restrict__ srow, const __half* __restrict__ g2,
        const float* __restrict__ dinv, const float* __restrict__ b2,
        const float* __restrict__ fcW, const float* __restrict__ fcb,
        float* __restrict__ out) {
    __shared__ float w[FO];
    __shared__ float bb[FO];
    __shared__ float fb;
    int t = threadIdx.x;
    if (t < FO) { w[t] = fcW[t]; bb[t] = b2[t]; }
    if (t == 0) fb = fcb[0];
    __syncthreads();
    int node = perm[blockIdx.x * 128 + (t >> 1)];
    int q = t & 1;
    if (node < 0) return;
    float di = dinv[node];
    float acc[8];
    {   // self-loop seed
        int4 raw = ((const int4*)(g2 + (long long)node * FO))[q];
        float2 f0 = unpack2(raw.x), f1 = unpack2(raw.y);
        float2 f2 = unpack2(raw.z), f3 = unpack2(raw.w);
        acc[0] = f0.x; acc[1] = f0.y; acc[2] = f1.x; acc[3] = f1.y;
        acc[4] = f2.x; acc[5] = f2.y; acc[6] = f3.x; acc[7] = f3.y;
    }
    int2 oc = offcnt[node];
    int s = oc.x, m = oc.y;
    int i = 0;
    for (; i + 3 < m; i += 4) {
        int r0 = srow[s + i];
        int r1 = srow[s + i + 1];
        int r2 = srow[s + i + 2];
        int r3 = srow[s + i + 3];
        int4 ra = ((const int4*)(g2 + (long long)r0 * FO))[q];
        int4 rb = ((const int4*)(g2 + (long long)r1 * FO))[q];
        int4 rc = ((const int4*)(g2 + (long long)r2 * FO))[q];
        int4 rd = ((const int4*)(g2 + (long long)r3 * FO))[q];
        float2 u;
        u = unpack2(ra.x); acc[0] += u.x; acc[1] += u.y;
        u = unpack2(ra.y); acc[2] += u.x; acc[3] += u.y;
        u = unpack2(ra.z); acc[4] += u.x; acc[5] += u.y;
        u = unpack2(ra.w); acc[6] += u.x; acc[7] += u.y;
        u = unpack2(rb.x); acc[0] += u.x; acc[1] += u.y;
        u = unpack2(rb.y); acc[2] += u.x; acc[3] += u.y;
        u = unpack2(rb.z); acc[4] += u.x; acc[5] += u.y;
        u = unpack2(rb.w); acc[6] += u.x; acc[7] += u.y;
        u = unpack2(rc.x); acc[0] += u.x; acc[1] += u.y;
        u = unpack2(rc.y); acc[2] += u.x; acc[3] += u.y;
        u = unpack2(rc.z); acc[4] += u.x; acc[5] += u.y;
        u = unpack2(rc.w); acc[6] += u.x; acc[7] += u.y;
        u = unpack2(rd.x); acc[0] += u.x; acc[1] += u.y;
        u = unpack2(rd.y); acc[2] += u.x; acc[3] += u.y;
        u = unpack2(rd.z); acc[4] += u.x; acc[5] += u.y;
        u = unpack2(rd.w); acc[6] += u.x; acc[7] += u.y;
    }
    for (; i < m; i++) {
        int r0 = srow[s + i];
        int4 ra = ((const int4*)(g2 + (long long)r0 * FO))[q];
        float2 u;
        u = unpack2(ra.x); acc[0] += u.x; acc[1] += u.y;
        u = unpack2(ra.y); acc[2] += u.x; acc[3] += u.y;
        u = unpack2(ra.z); acc[4] += u.x; acc[5] += u.y;
        u = unpack2(ra.w); acc[6] += u.x; acc[7] += u.y;
    }
    // x2 = relu(acc*di + b2[8q..]); partial dot with fcW
    float p = 0.f;
    #pragma unroll
    for (int j = 0; j < 8; j++) {
        float a = acc[j] * di + bb[8*q + j];
        p += (a > 0.f ? a : 0.f) * w[8*q + j];
    }
    p += __shfl_down(p, 1, 2);             // reduce the node's 2 lanes
    if (q == 0) out[node] = p + fb;
}

extern "C" void kernel_launch(void* const* d_in, const int* in_sizes, int n_in,
                              void* d_out, int out_size, void* d_ws, size_t ws_size,
                              hipStream_t stream) {
    const int*   edge = (const int*)d_in[0];        // [2, E] int32
    const float* x    = (const float*)d_in[1];      // [N, 16]
    const float* W1   = (const float*)d_in[2];      // [16, 32]
    const float* b1   = (const float*)d_in[3];      // [32]
    const float* W2   = (const float*)d_in[4];      // [32, 16]
    const float* b2   = (const float*)d_in[5];      // [16]
    const float* fcW  = (const float*)d_in[6];      // [16, 1]
    const float* fcb  = (const float*)d_in[7];      // [1]
    float* out = (float*)d_out;

    const int E = in_sizes[0] / 2;                  // 1600000
    const int n = NN;
    const int* row = edge;
    const int* col = edge + E;

    // workspace layout (4-byte units), regions 128-elem aligned:
    const size_t nA = (size_t)((n + 127) & ~127);
    char* wsb = (char*)d_ws;
    int2*  offcnt  = (int2*)wsb;                    // n int2
    float* dinv    = (float*)(offcnt + nA);         // n floats
    int*   perm    = (int*)(dinv + nA);             // NSLOT ints
    int*   bcursor = perm + ((NSLOT + 127) & ~127); // NBUCKET ints (pad 512)
    int*   srow    = bcursor + 512;                 // (NBUCKET+1)*CAP ints (+slack seg)
    int*   srowEnd = srow + (size_t)(NBUCKET + 1) * CAP;
    __half* g1     = (__half*)srowEnd;              // n*FH halfs (6.4 MB)
    __half* g2     = g1 + (size_t)n * FH;           // n*FO halfs (3.2 MB)

    const int B = 256;
    const int nChunkBlocks = (E + CHUNK - 1) / CHUNK;   // 196

    // 1. bcursor[b] = b*CAP
    init_kernel<<<2, B, 0, stream>>>(bcursor);
    // 2. phase A: bucket fill into fixed segments; per-block run reservation
    bucket_fill_kernel<<<nChunkBlocks, B, 0, stream>>>(row, col, bcursor, srow, E);
    // 3. phase B: per-bucket counting sort + degree perm + fused mm1
    bucket_sort_mm1_kernel<<<NBUCKET, B, 0, stream>>>(bcursor, srow, offcnt, dinv, perm, x, W1, g1, n);
    // 4. fused gather1 + relu/bias + mm2 + scale -> g2   (64 slots/block)
    gather_mm2_kernel<<<NSLOT / 64, B, 0, stream>>>(offcnt, perm, srow, g1, dinv, b1, W2, g2);
    // 5. fused gather2 + relu/bias + fc -> out            (128 slots/block)
    gather_fc_kernel<<<NSLOT / 128, B, 0, stream>>>(offcnt, perm, srow, g2, dinv, b2, fcW, fcb, out);
}

// Round 13
// 152.005 us; speedup vs baseline: 1.0826x; 1.0826x over previous
//
#include <hip/hip_runtime.h>
#include <hip/hip_fp16.h>

// GCN 2-layer forward. N=100000 nodes, E=1600000 directed edges.
// out[c] = relu( dinv[c] * ( sum_{r->c} g[r] + g[c] ) + b ),  g = (x@W)*dinv
// dinv = rsqrt(indeg+1) (self-loops folded in analytically).
// Round 13: revert to the round-10 configuration (best measured: 150.3 us).
// R11 (CHUNK 4096 / no-ebuf) and R12 (degree-ordered perm) both regressed:
// the gathers are bound by random L2/L3 line-transaction rate (structural),
// and the build is write-amp-optimal at >=16 entries/line per bucket run.

constexpr int NN  = 100000;
constexpr int FIN = 16;
constexpr int FH  = 32;   // hidden
constexpr int FO  = 16;   // layer-2 out

constexpr int BK      = 256;                     // nodes per bucket (col>>8)
constexpr int NBUCKET = (NN + BK - 1) / BK;      // 391
constexpr int CHUNK   = 8192;                    // edges per fill block (196 blocks)
constexpr int CAP     = 5376;                    // bucket segment capacity (mean 4092, +20 sigma)

static __device__ __forceinline__ int pack2(float a, float b) {
    __half2 t = __float22half2_rn(make_float2(a, b));
    return *reinterpret_cast<int*>(&t);
}
static __device__ __forceinline__ float2 unpack2(int v) {
    __half2 t = *reinterpret_cast<__half2*>(&v);
    return __half22float2(t);
}

// ---- init: bcursor[b] = b*CAP ----
__global__ void init_kernel(int* __restrict__ bcursor) {
    int b = blockIdx.x * blockDim.x + threadIdx.x;
    if (b < NBUCKET) bcursor[b] = b * CAP;
}

// ---- phase A: bucket fill into fixed segments. Per-block run reservation. ----
__global__ __launch_bounds__(256) void bucket_fill_kernel(
        const int* __restrict__ row, const int* __restrict__ col,
        int* __restrict__ bcursor, int* __restrict__ srow, int E) {
    __shared__ int bcnt[NBUCKET];
    __shared__ int bcur[NBUCKET];
    int t = threadIdx.x;
    int e0 = blockIdx.x * CHUNK;
    int m = E - e0; if (m > CHUNK) m = CHUNK;
    for (int b = t; b < NBUCKET; b += 256) bcnt[b] = 0;
    __syncthreads();
    for (int i = t; i < m; i += 256)
        atomicAdd(&bcnt[col[e0 + i] >> 8], 1);
    __syncthreads();
    for (int b = t; b < NBUCKET; b += 256) {
        int v = bcnt[b];
        bcur[b] = v ? atomicAdd(&bcursor[b], v) : 0;   // contiguous run for this block
    }
    __syncthreads();
    for (int i = t; i < m; i += 256) {
        int c = col[e0 + i];
        int r = row[e0 + i];
        int p = atomicAdd(&bcur[c >> 8], 1);
        srow[p] = ((c & (BK - 1)) << 17) | r;          // pack (c_local, r); r < 2^17
    }
}

// ---- phase B: per-bucket LDS counting sort; emits off/cnt/dinv AND g1 rows
// (mm1 fused: thread t owns node lo+t, its degree v is already in-register).
__global__ __launch_bounds__(256) void bucket_sort_mm1_kernel(
        const int* __restrict__ bcursor, int* __restrict__ srow,
        int* __restrict__ off, int* __restrict__ cnt, float* __restrict__ dinv,
        const float* __restrict__ x, const float* __restrict__ W1,
        __half* __restrict__ g1, int n) {
    __shared__ int ebuf[CAP];
    __shared__ int sorted[CAP];
    __shared__ int cnt2[BK];
    __shared__ int aux[BK];
    __shared__ float w1[FIN * FH];
    int t = threadIdx.x;
    for (int i = t; i < FIN * FH; i += 256) w1[i] = W1[i];
    int lo = blockIdx.x << 8;
    int nodes = n - lo; if (nodes > BK) nodes = BK;
    int s0 = blockIdx.x * CAP;
    int m = bcursor[blockIdx.x] - s0;                  // total edges in this bucket
    if (m > CAP) m = CAP;                              // paranoia guard (never hit)
    for (int i = t; i < m; i += 256) ebuf[i] = srow[s0 + i];
    cnt2[t] = 0;
    __syncthreads();
    for (int i = t; i < m; i += 256) atomicAdd(&cnt2[ebuf[i] >> 17], 1);
    __syncthreads();
    int v = cnt2[t];
    aux[t] = v;
    __syncthreads();
    for (int d = 1; d < BK; d <<= 1) {
        int a = (t >= d) ? aux[t - d] : 0;
        __syncthreads();
        aux[t] += a;
        __syncthreads();
    }
    int excl = aux[t] - v;
    cnt2[t] = excl;                                    // cursor for scatter
    float di = rsqrtf((float)v + 1.0f);
    if (t < nodes) {                                   // per-node CSR metadata, free
        off[lo + t]  = s0 + excl;
        cnt[lo + t]  = v;
        dinv[lo + t] = di;
    }
    __syncthreads();
    for (int i = t; i < m; i += 256) {
        int pv = ebuf[i];
        int p = atomicAdd(&cnt2[pv >> 17], 1);
        sorted[p] = pv & 0x1FFFF;
    }
    __syncthreads();
    for (int i = t; i < m; i += 256) srow[s0 + i] = sorted[i];
    // ---- fused mm1: g1[lo+t] = fp16( (x[lo+t] @ W1) * di ) ----
    if (t < nodes) {
        int nd = lo + t;
        float xi[FIN];
        const float4* xv = (const float4*)(x + (long long)nd * FIN);
        #pragma unroll
        for (int i = 0; i < FIN / 4; i++) {
            float4 vv = xv[i];
            xi[4*i] = vv.x; xi[4*i+1] = vv.y; xi[4*i+2] = vv.z; xi[4*i+3] = vv.w;
        }
        float h[FH];
        #pragma unroll
        for (int j = 0; j < FH; j++) h[j] = 0.f;
        #pragma unroll
        for (int i = 0; i < FIN; i++) {
            float xs = xi[i];
            #pragma unroll
            for (int j = 0; j < FH; j++) h[j] += xs * w1[i * FH + j];
        }
        int4* gv = (int4*)(g1 + (long long)nd * FH);   // 64 B row
        #pragma unroll
        for (int k = 0; k < 4; k++) {
            gv[k] = make_int4(pack2(h[8*k]*di,   h[8*k+1]*di),
                              pack2(h[8*k+2]*di, h[8*k+3]*di),
                              pack2(h[8*k+4]*di, h[8*k+5]*di),
                              pack2(h[8*k+6]*di, h[8*k+7]*di));
        }
    }
}

// ---- fused gather layer1 (fp16 rows) + relu/bias + mm2 + scale -> g2 (fp16) ----
// block = 256 threads = 64 nodes x 4 lanes (lane = 8 feats = int4 = 16 B)
constexpr int XS = 36;   // LDS stride: 16B-aligned writes, 2-way (free) reads
__global__ __launch_bounds__(256) void gather_mm2_kernel(
        const int* __restrict__ off, const int* __restrict__ cnt,
        const int* __restrict__ srow, const __half* __restrict__ g1,
        const float* __restrict__ dinv, const float* __restrict__ b1,
        const float* __restrict__ W2, __half* __restrict__ g2, int n) {
    __shared__ float xs[64 * XS];          // 64 nodes x 32 feats (stride 36)
    __shared__ float w[FH * FO];           // 32x16
    __shared__ float bb[FH];
    int t = threadIdx.x;
    for (int i = t; i < FH * FO; i += 256) w[i] = W2[i];
    if (t < FH) bb[t] = b1[t];
    int nl = t >> 2;                       // node-local 0..63
    int q = t & 3;                         // 8-feat group
    int node = blockIdx.x * 64 + nl;
    bool live = node < n;
    float acc[8] = {0.f,0.f,0.f,0.f,0.f,0.f,0.f,0.f};
    float di = 0.f;
    if (live) {
        di = dinv[node];
        {   // self-loop seed
            int4 raw = ((const int4*)(g1 + (long long)node * FH))[q];
            float2 f0 = unpack2(raw.x), f1 = unpack2(raw.y);
            float2 f2 = unpack2(raw.z), f3 = unpack2(raw.w);
            acc[0] = f0.x; acc[1] = f0.y; acc[2] = f1.x; acc[3] = f1.y;
            acc[4] = f2.x; acc[5] = f2.y; acc[6] = f3.x; acc[7] = f3.y;
        }
        int s = off[node];
        int m = cnt[node];
        int i = 0;
        for (; i + 3 < m; i += 4) {        // 4 indices then 4 16B rows in flight
            int r0 = srow[s + i];
            int r1 = srow[s + i + 1];
            int r2 = srow[s + i + 2];
            int r3 = srow[s + i + 3];
            int4 ra = ((const int4*)(g1 + (long long)r0 * FH))[q];
            int4 rb = ((const int4*)(g1 + (long long)r1 * FH))[q];
            int4 rc = ((const int4*)(g1 + (long long)r2 * FH))[q];
            int4 rd = ((const int4*)(g1 + (long long)r3 * FH))[q];
            float2 u;
            u = unpack2(ra.x); acc[0] += u.x; acc[1] += u.y;
            u = unpack2(ra.y); acc[2] += u.x; acc[3] += u.y;
            u = unpack2(ra.z); acc[4] += u.x; acc[5] += u.y;
            u = unpack2(ra.w); acc[6] += u.x; acc[7] += u.y;
            u = unpack2(rb.x); acc[0] += u.x; acc[1] += u.y;
            u = unpack2(rb.y); acc[2] += u.x; acc[3] += u.y;
            u = unpack2(rb.z); acc[4] += u.x; acc[5] += u.y;
            u = unpack2(rb.w); acc[6] += u.x; acc[7] += u.y;
            u = unpack2(rc.x); acc[0] += u.x; acc[1] += u.y;
            u = unpack2(rc.y); acc[2] += u.x; acc[3] += u.y;
            u = unpack2(rc.z); acc[4] += u.x; acc[5] += u.y;
            u = unpack2(rc.w); acc[6] += u.x; acc[7] += u.y;
            u = unpack2(rd.x); acc[0] += u.x; acc[1] += u.y;
            u = unpack2(rd.y); acc[2] += u.x; acc[3] += u.y;
            u = unpack2(rd.z); acc[4] += u.x; acc[5] += u.y;
            u = unpack2(rd.w); acc[6] += u.x; acc[7] += u.y;
        }
        for (; i < m; i++) {
            int r0 = srow[s + i];
            int4 ra = ((const int4*)(g1 + (long long)r0 * FH))[q];
            float2 u;
            u = unpack2(ra.x); acc[0] += u.x; acc[1] += u.y;
            u = unpack2(ra.y); acc[2] += u.x; acc[3] += u.y;
            u = unpack2(ra.z); acc[4] += u.x; acc[5] += u.y;
            u = unpack2(ra.w); acc[6] += u.x; acc[7] += u.y;
        }
    }
    __syncthreads();                       // w/bb loaded; also before xs write
    if (live) {
        // x1[8q..8q+7] = relu(acc*di + b1)
        float* xr = xs + nl * XS + 8 * q;
        #pragma unroll
        for (int j = 0; j < 8; j++) {
            float a = acc[j] * di + bb[8*q + j];
            xr[j] = a > 0.f ? a : 0.f;
        }
    }
    __syncthreads();
    if (live) {
        // lane q computes outputs k = 4q..4q+3 of x1 @ W2 (FO=16)
        const float* xr = xs + nl * XS;
        int k0 = 4 * q;
        float o0 = 0.f, o1 = 0.f, o2 = 0.f, o3 = 0.f;
        #pragma unroll
        for (int j = 0; j < FH; j++) {
            float xj = xr[j];
            const float* wr = w + j * FO + k0;
            o0 += xj * wr[0];
            o1 += xj * wr[1];
            o2 += xj * wr[2];
            o3 += xj * wr[3];
        }
        ((int2*)(g2 + (long long)node * FO))[q] =
            make_int2(pack2(o0 * di, o1 * di), pack2(o2 * di, o3 * di));
    }
}

// ---- fused gather layer2 (fp16 rows) + relu/bias + fc -> out ----
// block = 256 threads = 128 nodes x 2 lanes (lane = 8 feats = int4 = 16 B)
__global__ __launch_bounds__(256) void gather_fc_kernel(
        const int* __restrict__ off, const int* __restrict__ cnt,
        const int* __restrict__ srow, const __half* __restrict__ g2,
        const float* __restrict__ dinv, const float* __restrict__ b2,
        const float* __restrict__ fcW, const float* __restrict__ fcb,
        float* __restrict__ out, int n) {
    __shared__ float w[FO];
    __shared__ float bb[FO];
    __shared__ float fb;
    int t = threadIdx.x;
    if (t < FO) { w[t] = fcW[t]; bb[t] = b2[t]; }
    if (t == 0) fb = fcb[0];
    __syncthreads();
    int node = blockIdx.x * 128 + (t >> 1);
    int q = t & 1;
    if (node >= n) return;
    float di = dinv[node];
    float acc[8];
    {   // self-loop seed
        int4 raw = ((const int4*)(g2 + (long long)node * FO))[q];
        float2 f0 = unpack2(raw.x), f1 = unpack2(raw.y);
        float2 f2 = unpack2(raw.z), f3 = unpack2(raw.w);
        acc[0] = f0.x; acc[1] = f0.y; acc[2] = f1.x; acc[3] = f1.y;
        acc[4] = f2.x; acc[5] = f2.y; acc[6] = f3.x; acc[7] = f3.y;
    }
    int s = off[node];
    int m = cnt[node];
    int i = 0;
    for (; i + 3 < m; i += 4) {
        int r0 = srow[s + i];
        int r1 = srow[s + i + 1];
        int r2 = srow[s + i + 2];
        int r3 = srow[s + i + 3];
        int4 ra = ((const int4*)(g2 + (long long)r0 * FO))[q];
        int4 rb = ((const int4*)(g2 + (long long)r1 * FO))[q];
        int4 rc = ((const int4*)(g2 + (long long)r2 * FO))[q];
        int4 rd = ((const int4*)(g2 + (long long)r3 * FO))[q];
        float2 u;
        u = unpack2(ra.x); acc[0] += u.x; acc[1] += u.y;
        u = unpack2(ra.y); acc[2] += u.x; acc[3] += u.y;
        u = unpack2(ra.z); acc[4] += u.x; acc[5] += u.y;
        u = unpack2(ra.w); acc[6] += u.x; acc[7] += u.y;
        u = unpack2(rb.x); acc[0] += u.x; acc[1] += u.y;
        u = unpack2(rb.y); acc[2] += u.x; acc[3] += u.y;
        u = unpack2(rb.z); acc[4] += u.x; acc[5] += u.y;
        u = unpack2(rb.w); acc[6] += u.x; acc[7] += u.y;
        u = unpack2(rc.x); acc[0] += u.x; acc[1] += u.y;
        u = unpack2(rc.y); acc[2] += u.x; acc[3] += u.y;
        u = unpack2(rc.z); acc[4] += u.x; acc[5] += u.y;
        u = unpack2(rc.w); acc[6] += u.x; acc[7] += u.y;
        u = unpack2(rd.x); acc[0] += u.x; acc[1] += u.y;
        u = unpack2(rd.y); acc[2] += u.x; acc[3] += u.y;
        u = unpack2(rd.z); acc[4] += u.x; acc[5] += u.y;
        u = unpack2(rd.w); acc[6] += u.x; acc[7] += u.y;
    }
    for (; i < m; i++) {
        int r0 = srow[s + i];
        int4 ra = ((const int4*)(g2 + (long long)r0 * FO))[q];
        float2 u;
        u = unpack2(ra.x); acc[0] += u.x; acc[1] += u.y;
        u = unpack2(ra.y); acc[2] += u.x; acc[3] += u.y;
        u = unpack2(ra.z); acc[4] += u.x; acc[5] += u.y;
        u = unpack2(ra.w); acc[6] += u.x; acc[7] += u.y;
    }
    // x2 = relu(acc*di + b2[8q..]); partial dot with fcW
    float p = 0.f;
    #pragma unroll
    for (int j = 0; j < 8; j++) {
        float a = acc[j] * di + bb[8*q + j];
        p += (a > 0.f ? a : 0.f) * w[8*q + j];
    }
    p += __shfl_down(p, 1, 2);             // reduce the node's 2 lanes
    if (q == 0) out[node] = p + fb;
}

extern "C" void kernel_launch(void* const* d_in, const int* in_sizes, int n_in,
                              void* d_out, int out_size, void* d_ws, size_t ws_size,
                              hipStream_t stream) {
    const int*   edge = (const int*)d_in[0];        // [2, E] int32
    const float* x    = (const float*)d_in[1];      // [N, 16]
    const float* W1   = (const float*)d_in[2];      // [16, 32]
    const float* b1   = (const float*)d_in[3];      // [32]
    const float* W2   = (const float*)d_in[4];      // [32, 16]
    const float* b2   = (const float*)d_in[5];      // [16]
    const float* fcW  = (const float*)d_in[6];      // [16, 1]
    const float* fcb  = (const float*)d_in[7];      // [1]
    float* out = (float*)d_out;

    const int E = in_sizes[0] / 2;                  // 1600000
    const int n = NN;
    const int* row = edge;
    const int* col = edge + E;

    // workspace layout (4-byte units), regions 128-elem aligned:
    const size_t nA = (size_t)((n + 127) & ~127);
    char* wsb = (char*)d_ws;
    int*   cnt     = (int*)wsb;                     // n ints (per-node degree)
    int*   off     = cnt + nA;                      // n ints
    float* dinv    = (float*)(off + nA);            // n floats
    int*   bcursor = (int*)(dinv + nA);             // NBUCKET ints (pad 512)
    int*   srow    = bcursor + 512;                 // (NBUCKET+1)*CAP ints (+slack seg)
    int*   srowEnd = srow + (size_t)(NBUCKET + 1) * CAP;
    __half* g1     = (__half*)srowEnd;              // n*FH halfs (6.4 MB)
    __half* g2     = g1 + (size_t)n * FH;           // n*FO halfs (3.2 MB)

    const int B = 256;
    const int nChunkBlocks = (E + CHUNK - 1) / CHUNK;   // 196

    // 1. bcursor[b] = b*CAP
    init_kernel<<<2, B, 0, stream>>>(bcursor);
    // 2. phase A: bucket fill into fixed segments; per-block run reservation
    bucket_fill_kernel<<<nChunkBlocks, B, 0, stream>>>(row, col, bcursor, srow, E);
    // 3. phase B: per-bucket counting sort + fused mm1 -> off/cnt/dinv/g1
    bucket_sort_mm1_kernel<<<NBUCKET, B, 0, stream>>>(bcursor, srow, off, cnt, dinv, x, W1, g1, n);
    // 4. fused gather1 + relu/bias + mm2 + scale -> g2   (64 nodes/block)
    gather_mm2_kernel<<<(n + 63) / 64, B, 0, stream>>>(off, cnt, srow, g1, dinv, b1, W2, g2, n);
    // 5. fused gather2 + relu/bias + fc -> out            (128 nodes/block)
    gather_fc_kernel<<<(n + 127) / 128, B, 0, stream>>>(off, cnt, srow, g2, dinv, b2, fcW, fcb, out, n);
}